// Round 5
// baseline (9.878 us; speedup 1.0000x reference)
//
#include <hip/hip_runtime.h>
#include <math.h>

#define EMBED 1024

typedef float f32x4 __attribute__((ext_vector_type(4)));

__device__ __forceinline__ float dot4(f32x4 a, f32x4 b) {
    return a[0] * b[0] + a[1] * b[1] + a[2] * b[2] + a[3] * b[3];
}

// 512 blocks x 512 threads (8 waves). Wave w of block b computes the FULL
// gate preactivation for j = 2b + (w>>2), gate = w&3:
//   W_ih[row]·x + W_hh[row]·h + b_ih[row] + b_hh[row]   (row = gate*1024+j)
// 16 loads (8 KB weights + 8 KB operand reads) issued back-to-back per wave
// -> 2x bytes-in-flight vs previous structure, half the reductions.
__global__ __launch_bounds__(512) void lstm_step_kernel(
    const unsigned int* __restrict__ tok,     // low word of int64 token id
    const float* __restrict__ h_in,           // [EMBED]
    const float* __restrict__ c_in,           // [EMBED]
    const float* __restrict__ embed,          // [VOCAB, EMBED]
    const float* __restrict__ W_ih,           // [4*EMBED, EMBED]
    const float* __restrict__ W_hh,           // [4*EMBED, EMBED]
    const float* __restrict__ b_ih,           // [4*EMBED]
    const float* __restrict__ b_hh,           // [4*EMBED]
    float* __restrict__ out)                  // [2*EMBED]: h_new | c_new
{
    __shared__ float part[8];                 // gate preacts: [jj*4 + gate]

    const int tid  = threadIdx.x;
    const int w    = tid >> 6;                 // wave 0..7
    const int lane = tid & 63;
    const int jj   = w >> 2;                   // 0/1: which j this wave serves
    const int gate = w & 3;                    // 0..3 -> i,f,g,o
    const int j    = (blockIdx.x << 1) + jj;
    const int row  = gate * EMBED + j;

    // ---- Issue ALL 8 weight loads back-to-back (8 KB in flight per wave) ----
    const f32x4* wi = (const f32x4*)(W_ih + (size_t)row * EMBED);
    const f32x4* wh = (const f32x4*)(W_hh + (size_t)row * EMBED);
    f32x4 a0 = __builtin_nontemporal_load(wi + lane);
    f32x4 a1 = __builtin_nontemporal_load(wi + lane + 64);
    f32x4 a2 = __builtin_nontemporal_load(wi + lane + 128);
    f32x4 a3 = __builtin_nontemporal_load(wi + lane + 192);
    f32x4 c0 = __builtin_nontemporal_load(wh + lane);
    f32x4 c1 = __builtin_nontemporal_load(wh + lane + 64);
    f32x4 c2 = __builtin_nontemporal_load(wh + lane + 128);
    f32x4 c3 = __builtin_nontemporal_load(wh + lane + 192);

    const float bias = b_ih[row] + b_hh[row];  // wave-uniform scalar loads

    // ---- Operand rows: x = embed[tok] (token-dependent), h. L2-hot after
    // first touch (shared by all 4096 waves). ----
    const unsigned int t = tok[0];
    const f32x4* x4 = (const f32x4*)(embed + (size_t)t * EMBED);
    const f32x4* h4 = (const f32x4*)h_in;
    f32x4 x0 = x4[lane];
    f32x4 x1 = x4[lane + 64];
    f32x4 x2 = x4[lane + 128];
    f32x4 x3 = x4[lane + 192];
    f32x4 h0 = h4[lane];
    f32x4 h1 = h4[lane + 64];
    f32x4 h2 = h4[lane + 128];
    f32x4 h3 = h4[lane + 192];

    float acc = dot4(a0, x0) + dot4(a1, x1) + dot4(a2, x2) + dot4(a3, x3)
              + dot4(c0, h0) + dot4(c1, h1) + dot4(c2, h2) + dot4(c3, h3);

    // 64-lane butterfly reduction
    #pragma unroll
    for (int off = 32; off > 0; off >>= 1)
        acc += __shfl_xor(acc, off);

    if (lane == 0)
        part[w] = acc + bias;
    __syncthreads();

    // One epilogue thread per j: tid 0 -> jj=0, tid 256 -> jj=1.
    if ((tid & 255) == 0) {
        const int base = (tid >> 6);           // 0 or 4
        const int jm   = (blockIdx.x << 1) + (tid >> 8);
        const float gi = part[base + 0];
        const float gf = part[base + 1];
        const float gg = part[base + 2];
        const float go = part[base + 3];
        const float i = 1.f / (1.f + __expf(-gi));
        const float f = 1.f / (1.f + __expf(-gf));
        const float e2g = __expf(2.f * gg);
        const float g = (e2g - 1.f) / (e2g + 1.f);      // tanh
        const float o = 1.f / (1.f + __expf(-go));
        const float c_new = f * c_in[jm] + i * g;
        const float e2c = __expf(2.f * c_new);
        const float tc  = (e2c - 1.f) / (e2c + 1.f);    // tanh
        out[jm]         = o * tc;   // h_new (tuple order first)
        out[EMBED + jm] = c_new;    // c_new
    }
}

extern "C" void kernel_launch(void* const* d_in, const int* in_sizes, int n_in,
                              void* d_out, int out_size, void* d_ws, size_t ws_size,
                              hipStream_t stream) {
    const unsigned int* tok  = (const unsigned int*)d_in[0]; // int64 low word (LE)
    const float* h_in  = (const float*)d_in[1];
    const float* c_in  = (const float*)d_in[2];
    const float* embed = (const float*)d_in[3];
    const float* W_ih  = (const float*)d_in[4];
    const float* W_hh  = (const float*)d_in[5];
    const float* b_ih  = (const float*)d_in[6];
    const float* b_hh  = (const float*)d_in[7];
    float* out = (float*)d_out;

    lstm_step_kernel<<<EMBED / 2, 512, 0, stream>>>(
        tok, h_in, c_in, embed, W_ih, W_hh, b_ih, b_hh, out);
}

// Round 6
// 9.703 us; speedup vs baseline: 1.0180x; 1.0180x over previous
//
#include <hip/hip_runtime.h>
#include <math.h>

#define EMBED 1024

typedef float f32x4 __attribute__((ext_vector_type(4)));

__device__ __forceinline__ float dot4(f32x4 a, f32x4 b) {
    return a[0] * b[0] + a[1] * b[1] + a[2] * b[2] + a[3] * b[3];
}

// 256 blocks x 512 threads (8 waves). Block b owns j in {4b..4b+3}.
// Wave w (jj=w>>2, gate=w&3) computes TWO full gate preactivations:
//   it=0: j = 4b + jj,  it=1: j = 4b + 2 + jj     (row = gate*1024 + j)
// All 16 weight loads (16 KB/wave) are issued before either compute
// (software pipeline); operand rows x,h are loaded once and reused.
__global__ __launch_bounds__(512) void lstm_step_kernel(
    const unsigned int* __restrict__ tok,     // low word of int64 token id
    const float* __restrict__ h_in,           // [EMBED]
    const float* __restrict__ c_in,           // [EMBED]
    const float* __restrict__ embed,          // [VOCAB, EMBED]
    const float* __restrict__ W_ih,           // [4*EMBED, EMBED]
    const float* __restrict__ W_hh,           // [4*EMBED, EMBED]
    const float* __restrict__ b_ih,           // [4*EMBED]
    const float* __restrict__ b_hh,           // [4*EMBED]
    float* __restrict__ out)                  // [2*EMBED]: h_new | c_new
{
    __shared__ float part[16];                // [it*8 + jj*4 + gate]

    const int tid  = threadIdx.x;
    const int w    = tid >> 6;                 // wave 0..7  (w = jj*4 + gate)
    const int lane = tid & 63;
    const int gate = w & 3;
    const int jj   = w >> 2;
    const int j0   = (blockIdx.x << 2) + jj;   // iteration 0
    const int j1   = j0 + 2;                   // iteration 1
    const int row0 = gate * EMBED + j0;
    const int row1 = gate * EMBED + j1;

    const f32x4* wi0 = (const f32x4*)(W_ih + (size_t)row0 * EMBED);
    const f32x4* wh0 = (const f32x4*)(W_hh + (size_t)row0 * EMBED);
    const f32x4* wi1 = (const f32x4*)(W_ih + (size_t)row1 * EMBED);
    const f32x4* wh1 = (const f32x4*)(W_hh + (size_t)row1 * EMBED);

    // ---- Issue ALL weight loads for BOTH iterations (16 KB in flight) ----
    f32x4 a0 = __builtin_nontemporal_load(wi0 + lane);
    f32x4 a1 = __builtin_nontemporal_load(wi0 + lane + 64);
    f32x4 a2 = __builtin_nontemporal_load(wi0 + lane + 128);
    f32x4 a3 = __builtin_nontemporal_load(wi0 + lane + 192);
    f32x4 c0 = __builtin_nontemporal_load(wh0 + lane);
    f32x4 c1 = __builtin_nontemporal_load(wh0 + lane + 64);
    f32x4 c2 = __builtin_nontemporal_load(wh0 + lane + 128);
    f32x4 c3 = __builtin_nontemporal_load(wh0 + lane + 192);
    f32x4 d0 = __builtin_nontemporal_load(wi1 + lane);
    f32x4 d1 = __builtin_nontemporal_load(wi1 + lane + 64);
    f32x4 d2 = __builtin_nontemporal_load(wi1 + lane + 128);
    f32x4 d3 = __builtin_nontemporal_load(wi1 + lane + 192);
    f32x4 e0 = __builtin_nontemporal_load(wh1 + lane);
    f32x4 e1 = __builtin_nontemporal_load(wh1 + lane + 64);
    f32x4 e2 = __builtin_nontemporal_load(wh1 + lane + 128);
    f32x4 e3 = __builtin_nontemporal_load(wh1 + lane + 192);

    const float bias0 = b_ih[row0] + b_hh[row0];   // wave-uniform scalars
    const float bias1 = b_ih[row1] + b_hh[row1];

    // ---- Operand rows loaded ONCE, reused by both iterations (L2-hot) ----
    const unsigned int t = tok[0];
    const f32x4* x4 = (const f32x4*)(embed + (size_t)t * EMBED);
    const f32x4* h4 = (const f32x4*)h_in;
    f32x4 x0 = x4[lane];
    f32x4 x1 = x4[lane + 64];
    f32x4 x2 = x4[lane + 128];
    f32x4 x3 = x4[lane + 192];
    f32x4 h0 = h4[lane];
    f32x4 h1 = h4[lane + 64];
    f32x4 h2 = h4[lane + 128];
    f32x4 h3 = h4[lane + 192];

    // ---- Iteration 0 compute + reduce ----
    float acc0 = dot4(a0, x0) + dot4(a1, x1) + dot4(a2, x2) + dot4(a3, x3)
               + dot4(c0, h0) + dot4(c1, h1) + dot4(c2, h2) + dot4(c3, h3);
    #pragma unroll
    for (int off = 32; off > 0; off >>= 1)
        acc0 += __shfl_xor(acc0, off);
    if (lane == 0)
        part[w] = acc0 + bias0;

    // ---- Iteration 1 compute + reduce ----
    float acc1 = dot4(d0, x0) + dot4(d1, x1) + dot4(d2, x2) + dot4(d3, x3)
               + dot4(e0, h0) + dot4(e1, h1) + dot4(e2, h2) + dot4(e3, h3);
    #pragma unroll
    for (int off = 32; off > 0; off >>= 1)
        acc1 += __shfl_xor(acc1, off);
    if (lane == 0)
        part[8 + w] = acc1 + bias1;

    __syncthreads();

    // Epilogue: 4 threads, one per j. t: it = t>>1, jj2 = t&1.
    if (tid < 4) {
        const int it   = tid >> 1;
        const int jj2  = tid & 1;
        const int base = it * 8 + jj2 * 4;
        const int jm   = (blockIdx.x << 2) + (it << 1) + jj2;
        const float gi = part[base + 0];
        const float gf = part[base + 1];
        const float gg = part[base + 2];
        const float go = part[base + 3];
        const float i = 1.f / (1.f + __expf(-gi));
        const float f = 1.f / (1.f + __expf(-gf));
        const float e2g = __expf(2.f * gg);
        const float g = (e2g - 1.f) / (e2g + 1.f);      // tanh
        const float o = 1.f / (1.f + __expf(-go));
        const float c_new = f * c_in[jm] + i * g;
        const float e2c = __expf(2.f * c_new);
        const float tc  = (e2c - 1.f) / (e2c + 1.f);    // tanh
        out[jm]         = o * tc;   // h_new (tuple order first)
        out[EMBED + jm] = c_new;    // c_new
    }
}

extern "C" void kernel_launch(void* const* d_in, const int* in_sizes, int n_in,
                              void* d_out, int out_size, void* d_ws, size_t ws_size,
                              hipStream_t stream) {
    const unsigned int* tok  = (const unsigned int*)d_in[0]; // int64 low word (LE)
    const float* h_in  = (const float*)d_in[1];
    const float* c_in  = (const float*)d_in[2];
    const float* embed = (const float*)d_in[3];
    const float* W_ih  = (const float*)d_in[4];
    const float* W_hh  = (const float*)d_in[5];
    const float* b_ih  = (const float*)d_in[6];
    const float* b_hh  = (const float*)d_in[7];
    float* out = (float*)d_out;

    lstm_step_kernel<<<EMBED / 4, 512, 0, stream>>>(
        tok, h_in, c_in, embed, W_ih, W_hh, b_ih, b_hh, out);
}